// Round 6
// baseline (270.755 us; speedup 1.0000x reference)
//
#include <hip/hip_runtime.h>

// MHSA: B=2, S=2048, D=1024, H=16, hd=64. fp32 in/out, bf16 MFMA internally.
// cvt(all) -> gemm_direct(Q*SC,K + V^T split, NO LDS) -> flash attn (q=64/wave, LDS-lean)
//          -> gemm_direct(+bias)

typedef __attribute__((ext_vector_type(8))) short short8;
typedef __attribute__((ext_vector_type(4))) float f32x4;
typedef unsigned short ushort_t;
typedef unsigned int uint32;

#define AS1 __attribute__((address_space(1)))
#define AS3 __attribute__((address_space(3)))

__device__ __forceinline__ void gload_lds16(const void* gp, void* lp) {
    __builtin_amdgcn_global_load_lds((const AS1 void*)gp, (AS3 void*)lp, 16, 0, 0);
}

#if __has_builtin(__builtin_amdgcn_exp2f)
#define EXP2F(x) __builtin_amdgcn_exp2f(x)
#else
#define EXP2F(x) exp2f(x)
#endif

__device__ __forceinline__ uint32 rhu(float f) { return __float_as_uint(f) + 0x8000u; }
#if __has_builtin(__builtin_amdgcn_perm)
__device__ __forceinline__ uint32 pk2bf(float a, float b) {
    return __builtin_amdgcn_perm(rhu(b), rhu(a), 0x07060302u);
}
#else
__device__ __forceinline__ uint32 pk2bf(float a, float b) {
    return (rhu(a) >> 16) | (rhu(b) & 0xffff0000u);
}
#endif
__device__ __forceinline__ ushort_t f2bf(float f) { return (ushort_t)(rhu(f) >> 16); }

// ---------------- fused fp32 -> bf16 convert ----------------
__global__ void cvt_all(const float* __restrict__ x, ushort_t* __restrict__ xb,
                        const float* __restrict__ wq, ushort_t* __restrict__ wqb,
                        const float* __restrict__ wo, ushort_t* __restrict__ wob) {
    int blk = blockIdx.x;
    const float* in; ushort_t* out;
    if (blk < 4096)      { in = x;  out = xb;  }
    else if (blk < 7168) { in = wq; out = wqb; blk -= 4096; }
    else                 { in = wo; out = wob; blk -= 7168; }
    const int i = (blk * 256 + threadIdx.x) * 4;
    const float4 v = *(const float4*)(in + i);
    uint2 pk;
    pk.x = pk2bf(v.x, v.y);
    pk.y = pk2bf(v.z, v.w);
    *(uint2*)(out + i) = pk;
}

// ---------------- C = A * B^T, NO LDS: direct global->VGPR frag loads ----------------
// 128x128 block, 4 waves 2x2 of 64x64. Frag rows are 16 dense 64B segments -> coalesced,
// tiles are L2-resident. 2-deep software pipeline (load next 32-k while MFMA current).
// Epilogues: bf16 (Q cols scaled) | fp32+bias | V^T split (cols>=2048).
__global__ __launch_bounds__(256, 3)
void gemm_bt_direct(const ushort_t* __restrict__ A, const ushort_t* __restrict__ B,
                    ushort_t* __restrict__ Cb, float* __restrict__ Cf,
                    const float* __restrict__ bias, ushort_t* __restrict__ vT,
                    int M, int N, int K, int ldc, float qScale) {
    const int tid = threadIdx.x;
    const int wave = tid >> 6, lane = tid & 63;
    const int quad = lane >> 4, l16 = lane & 15;
    const int wr = wave >> 1, wc = wave & 1;
    const int mBase = blockIdx.y * 128, nBase = blockIdx.x * 128;

    f32x4 acc[4][4];
#pragma unroll
    for (int i = 0; i < 4; i++)
#pragma unroll
        for (int j = 0; j < 4; j++) acc[i][j] = (f32x4){0.f, 0.f, 0.f, 0.f};

    const ushort_t* aP[4];
    const ushort_t* bP[4];
#pragma unroll
    for (int i = 0; i < 4; i++) {
        aP[i] = A + (size_t)(mBase + wr * 64 + i * 16 + l16) * K + quad * 8;
        bP[i] = B + (size_t)(nBase + wc * 64 + i * 16 + l16) * K + quad * 8;
    }

    short8 a0[4], b0[4], a1[4], b1[4];
#pragma unroll
    for (int i = 0; i < 4; i++) { a0[i] = *(const short8*)(aP[i]); b0[i] = *(const short8*)(bP[i]); }

#define G_MFMA(aa, bb)                                                                     \
    _Pragma("unroll") for (int i = 0; i < 4; i++)                                          \
        _Pragma("unroll") for (int j = 0; j < 4; j++)                                      \
            acc[i][j] = __builtin_amdgcn_mfma_f32_16x16x32_bf16(aa[i], bb[j], acc[i][j], 0, 0, 0);

    for (int k0 = 0; k0 < K; k0 += 64) {
#pragma unroll
        for (int i = 0; i < 4; i++) {
            a1[i] = *(const short8*)(aP[i] + k0 + 32);
            b1[i] = *(const short8*)(bP[i] + k0 + 32);
        }
        G_MFMA(a0, b0);
        // last prefetch reads at k=K (next row start) — within d_ws, never used
#pragma unroll
        for (int i = 0; i < 4; i++) {
            a0[i] = *(const short8*)(aP[i] + k0 + 64);
            b0[i] = *(const short8*)(bP[i] + k0 + 64);
        }
        G_MFMA(a1, b1);
    }

    if (vT && nBase >= 2048) {
        // V block -> vT[(b*16+h)*64+d][s], packed 8B along s (C-layout r runs along s)
#pragma unroll
        for (int i = 0; i < 4; i++)
#pragma unroll
            for (int j = 0; j < 4; j++) {
                const int row0 = mBase + wr * 64 + i * 16 + quad * 4;
                const int col = nBase + wc * 64 + j * 16 + l16 - 2048;
                const int b = row0 >> 11, s0 = row0 & 2047;
                uint2 pk;
                pk.x = pk2bf(acc[i][j][0], acc[i][j][1]);
                pk.y = pk2bf(acc[i][j][2], acc[i][j][3]);
                *(uint2*)(vT + ((size_t)(b * 16) * 64 + col) * 2048 + s0) = pk;
            }
        return;
    }
    const float cs = (vT && nBase < 1024) ? qScale : 1.0f;  // SCALE*log2e folded into Q
#pragma unroll
    for (int i = 0; i < 4; i++)
#pragma unroll
        for (int j = 0; j < 4; j++)
#pragma unroll
            for (int r = 0; r < 4; r++) {
                const int row = mBase + wr * 64 + i * 16 + quad * 4 + r;
                const int col = nBase + wc * 64 + j * 16 + l16;
                if (Cb) Cb[(size_t)row * ldc + col] = f2bf(acc[i][j][r] * cs);
                else    Cf[(size_t)row * ldc + col] = acc[i][j][r] + bias[col];
            }
}

// ---------------- fused flash attention, q=64/wave ----------------
// 512 thr = 8 waves = 4 q-groups x 2 key-halves. Bq=256, key-tile 64 (dbuf K+V).
// Every K/V/P b128 read feeds 4 MFMAs (qt=4 register blocking) — attacks the LDS
// bandwidth bound. grid (8,32) = 256 blocks = 1/CU. LDS exactly 64 KB.
// smem ushort layout: [0,8192) K dbuf | [8192,16384) V^T dbuf | [16384,32768) lP
// (lP region doubles as Q staging before the loop, and all of smem as reduction
// scratch after it).
__global__ __launch_bounds__(512, 2)
void attn_flash(const ushort_t* __restrict__ qk, const ushort_t* __restrict__ vT,
                ushort_t* __restrict__ o) {
    __shared__ ushort_t smem[32768];

    const int tid = threadIdx.x;
    const int wave = tid >> 6, lane = tid & 63;
    const int quad = lane >> 4, l16 = lane & 15;
    const int qg = wave & 3, kg = wave >> 2;
    const int bh = blockIdx.y, b = bh >> 4, h = bh & 15;
    const size_t rowBase = (size_t)b * 2048;
    const int qCol = h * 64, kCol = 1024 + h * 64;
    const int qRow0 = blockIdx.x * 256;
    const int swz = l16 & 7;

    ushort_t* lP = smem + 16384 + wave * 2048;  // [64 q][32 k], 16B-group XOR swizzled

    // ---- stage Q 256x64 (pre-scaled by SC) into lP region, pull B-frags ----
    {
        const int rl = wave * 8 + (lane >> 3);
#pragma unroll
        for (int cc = 0; cc < 4; cc++) {
            const int qr = cc * 64 + rl;
            gload_lds16(qk + (rowBase + qRow0 + qr) * 2048 + qCol + (((lane & 7) ^ (qr & 7)) * 8),
                        smem + 16384 + (cc * 8 + wave) * 512);
        }
    }
    __syncthreads();
    short8 qf[4][2];
#pragma unroll
    for (int qt = 0; qt < 4; qt++)
#pragma unroll
        for (int ks = 0; ks < 2; ks++)
            qf[qt][ks] = *(const short8*)(smem + 16384 + (qg * 64 + qt * 16 + l16) * 64 +
                                          (((ks * 4 + quad) ^ swz) * 8));
    __syncthreads();  // Q reads done; lP region free

    short8 onesA;
#pragma unroll
    for (int i = 0; i < 8; i++) onesA[i] = (short)0x3F80;

    f32x4 oacc[4][4];  // [dt][qt]
    f32x4 lacc[4];     // [qt], rows replicate l
#pragma unroll
    for (int dt = 0; dt < 4; dt++) {
        lacc[dt] = (f32x4){0.f, 0.f, 0.f, 0.f};
#pragma unroll
        for (int qt = 0; qt < 4; qt++) oacc[dt][qt] = (f32x4){0.f, 0.f, 0.f, 0.f};
    }

    // staging: 64 rows x 8 chunks = 512 loads = 1 per thread per buffer
    const int sr = wave * 8 + (lane >> 3);
    const int sch = ((lane & 7) ^ (sr & 7)) * 8;
    const ushort_t* kptr = qk + (rowBase + sr) * 2048 + kCol + sch;
    const ushort_t* vptr = vT + ((size_t)bh * 64 + sr) * 2048 + sch;

#define AT_STAGE(buf, kt)                                                            \
    {                                                                                \
        gload_lds16(kptr + (size_t)(kt) * 64 * 2048, smem + (buf) * 4096 + wave * 512); \
        gload_lds16(vptr + (kt) * 64, smem + 8192 + (buf) * 4096 + wave * 512);      \
    }

    AT_STAGE(0, 0);
    for (int kt = 0; kt < 32; kt++) {
        const int cur = kt & 1;
        __syncthreads();  // drains tile kt (issued one iteration ago)
        if (kt < 31) AT_STAGE(cur ^ 1, kt + 1);
        const ushort_t* lK = smem + cur * 4096;
        const ushort_t* lV = smem + 8192 + cur * 4096;

        // ---- S^T = K·Q^T on this wave's 32 keys x 64 q: 4 reads, 16 MFMA ----
        f32x4 sacc[2][4];  // [mh][qt]
#pragma unroll
        for (int mh = 0; mh < 2; mh++) {
            const int krow = kg * 32 + mh * 16 + l16;
            const short8 k0 = *(const short8*)(lK + krow * 64 + ((quad ^ swz) * 8));
            const short8 k1 = *(const short8*)(lK + krow * 64 + (((4 + quad) ^ swz) * 8));
#pragma unroll
            for (int qt = 0; qt < 4; qt++) {
                f32x4 t = (f32x4){0.f, 0.f, 0.f, 0.f};
                t = __builtin_amdgcn_mfma_f32_16x16x32_bf16(k0, qf[qt][0], t, 0, 0, 0);
                t = __builtin_amdgcn_mfma_f32_16x16x32_bf16(k1, qf[qt][1], t, 0, 0, 0);
                sacc[mh][qt] = t;
            }
        }

        // ---- P = exp2(S^T) -> lP (16B-group swizzle keeps writes conflict-free) ----
#pragma unroll
        for (int qt = 0; qt < 4; qt++)
#pragma unroll
            for (int mh = 0; mh < 2; mh++) {
                const f32x4 s = sacc[mh][qt];
                uint2 pk;
                pk.x = pk2bf(EXP2F(s[0]), EXP2F(s[1]));
                pk.y = pk2bf(EXP2F(s[2]), EXP2F(s[3]));
                *(uint2*)(lP + (qt * 16 + l16) * 32 +
                          (((mh * 2 + (quad >> 1)) ^ (l16 & 3)) * 8 + (quad & 1) * 4)) = pk;
            }

        // ---- P·V (+ones·P for l): 8 reads feed 20 MFMA ----
        short8 pf[4];
#pragma unroll
        for (int qt = 0; qt < 4; qt++) {
            pf[qt] = *(const short8*)(lP + (qt * 16 + l16) * 32 + ((quad ^ (l16 & 3)) * 8));
            lacc[qt] = __builtin_amdgcn_mfma_f32_16x16x32_bf16(onesA, pf[qt], lacc[qt], 0, 0, 0);
        }
#pragma unroll
        for (int dt = 0; dt < 4; dt++) {
            const short8 vf = *(const short8*)(lV + (dt * 16 + l16) * 64 +
                                               (((kg * 4 + quad) ^ swz) * 8));
#pragma unroll
            for (int qt = 0; qt < 4; qt++)
                oacc[dt][qt] = __builtin_amdgcn_mfma_f32_16x16x32_bf16(vf, pf[qt], oacc[dt][qt], 0, 0, 0);
        }
    }

    // ---- epilogue: reduce the two key-halves (kg) through LDS, write O ----
    float* red = (float*)smem;
    __syncthreads();
    if (kg == 1) {
#pragma unroll
        for (int qt = 0; qt < 4; qt++) red[(qg * 4 + qt) * 64 + lane] = lacc[qt][0];
    }
    __syncthreads();
    float linv[4];
    if (kg == 0) {
#pragma unroll
        for (int qt = 0; qt < 4; qt++)
            linv[qt] = 1.0f / (lacc[qt][0] + red[(qg * 4 + qt) * 64 + lane]);
    }
    __syncthreads();  // l reads done before oacc overwrites
    if (kg == 1) {
#pragma unroll
        for (int dt = 0; dt < 4; dt++)
#pragma unroll
            for (int qt = 0; qt < 4; qt++)
                *(f32x4*)(red + (((qg * 4 + dt) * 4 + qt) * 64 + lane) * 4) = oacc[dt][qt];
    }
    __syncthreads();
    if (kg == 0) {
#pragma unroll
        for (int qt = 0; qt < 4; qt++) {
            const size_t row = rowBase + qRow0 + qg * 64 + qt * 16 + l16;
#pragma unroll
            for (int dt = 0; dt < 4; dt++) {
                const f32x4 r = *(const f32x4*)(red + (((qg * 4 + dt) * 4 + qt) * 64 + lane) * 4);
                uint2 pk;
                pk.x = pk2bf((oacc[dt][qt][0] + r[0]) * linv[qt],
                             (oacc[dt][qt][1] + r[1]) * linv[qt]);
                pk.y = pk2bf((oacc[dt][qt][2] + r[2]) * linv[qt],
                             (oacc[dt][qt][3] + r[3]) * linv[qt]);
                *(uint2*)(o + row * 1024 + h * 64 + dt * 16 + quad * 4) = pk;
            }
        }
    }
}

extern "C" void kernel_launch(void* const* d_in, const int* in_sizes, int n_in,
                              void* d_out, int out_size, void* d_ws, size_t ws_size,
                              hipStream_t stream) {
    const float* x    = (const float*)d_in[0];
    const float* Wqkv = (const float*)d_in[1];
    const float* Wout = (const float*)d_in[2];
    const float* bout = (const float*)d_in[3];
    float* out = (float*)d_out;

    ushort_t* xb    = (ushort_t*)d_ws;                    // 4096*1024
    ushort_t* wqkvb = xb + (size_t)4096 * 1024;           // 3072*1024
    ushort_t* woutb = wqkvb + (size_t)3072 * 1024;        // 1024*1024
    ushort_t* qkb   = woutb + (size_t)1024 * 1024;        // 4096*2048 (Q*SC, K)
    ushort_t* vTb   = qkb + (size_t)4096 * 2048;          // 32*64*2048 (V^T)
    ushort_t* ob    = xb;                                 // alias: x dead after GEMM1

    const float SC = 0.125f * 1.44269504089f;  // SCALE * log2(e)

    cvt_all<<<8192, 256, 0, stream>>>(x, xb, Wqkv, wqkvb, Wout, woutb);
    gemm_bt_direct<<<dim3(24, 32), 256, 0, stream>>>(xb, wqkvb, qkb, nullptr, nullptr, vTb,
                                                     4096, 3072, 1024, 2048, SC);
    attn_flash<<<dim3(8, 32), 512, 0, stream>>>(qkb, vTb, ob);
    gemm_bt_direct<<<dim3(8, 32), 256, 0, stream>>>(ob, woutb, nullptr, out, bout, nullptr,
                                                    4096, 1024, 1024, 1024, 1.0f);
}

// Round 7
// 181.399 us; speedup vs baseline: 1.4926x; 1.4926x over previous
//
#include <hip/hip_runtime.h>

// MHSA: B=2, S=2048, D=1024, H=16, hd=64. fp32 in/out, bf16 MFMA internally.
// cvt(all) -> gemm_qkv(Q*SC,K + V^T split, LDS dbuf) -> flash attn (S^T, qt=2, key-split waves)
//          -> gemm_out(+bias, LDS dbuf)

typedef __attribute__((ext_vector_type(8))) short short8;
typedef __attribute__((ext_vector_type(4))) float f32x4;
typedef unsigned short ushort_t;
typedef unsigned int uint32;

#define AS1 __attribute__((address_space(1)))
#define AS3 __attribute__((address_space(3)))

__device__ __forceinline__ void gload_lds16(const void* gp, void* lp) {
    __builtin_amdgcn_global_load_lds((const AS1 void*)gp, (AS3 void*)lp, 16, 0, 0);
}

#if __has_builtin(__builtin_amdgcn_exp2f)
#define EXP2F(x) __builtin_amdgcn_exp2f(x)
#else
#define EXP2F(x) exp2f(x)
#endif

__device__ __forceinline__ uint32 rhu(float f) { return __float_as_uint(f) + 0x8000u; }
#if __has_builtin(__builtin_amdgcn_perm)
__device__ __forceinline__ uint32 pk2bf(float a, float b) {
    return __builtin_amdgcn_perm(rhu(b), rhu(a), 0x07060302u);
}
#else
__device__ __forceinline__ uint32 pk2bf(float a, float b) {
    return (rhu(a) >> 16) | (rhu(b) & 0xffff0000u);
}
#endif
__device__ __forceinline__ ushort_t f2bf(float f) { return (ushort_t)(rhu(f) >> 16); }

// ---------------- fused fp32 -> bf16 convert ----------------
__global__ void cvt_all(const float* __restrict__ x, ushort_t* __restrict__ xb,
                        const float* __restrict__ wq, ushort_t* __restrict__ wqb,
                        const float* __restrict__ wo, ushort_t* __restrict__ wob) {
    int blk = blockIdx.x;
    const float* in; ushort_t* out;
    if (blk < 4096)      { in = x;  out = xb;  }
    else if (blk < 7168) { in = wq; out = wqb; blk -= 4096; }
    else                 { in = wo; out = wob; blk -= 7168; }
    const int i = (blk * 256 + threadIdx.x) * 4;
    const float4 v = *(const float4*)(in + i);
    uint2 pk;
    pk.x = pk2bf(v.x, v.y);
    pk.y = pk2bf(v.z, v.w);
    *(uint2*)(out + i) = pk;
}

// ---------------- GEMM1: qkv = x·Wqkv^T, 128x128 tile, BK=32, dbuf (round-5) ----------------
__global__ __launch_bounds__(256, 2)
void gemm_qkv(const ushort_t* __restrict__ A, const ushort_t* __restrict__ B,
              ushort_t* __restrict__ Cb, ushort_t* __restrict__ vT,
              int M, int N, int K, int ldc, float qScale) {
    __shared__ ushort_t lA[2][128 * 32];
    __shared__ ushort_t lB[2][128 * 32];
    const int tid = threadIdx.x;
    const int wave = tid >> 6, lane = tid & 63;
    const int quad = lane >> 4, l16 = lane & 15;
    const int wr = wave >> 1, wc = wave & 1;
    const int mBase = blockIdx.y * 128, nBase = blockIdx.x * 128;

    f32x4 acc[4][4];
#pragma unroll
    for (int i = 0; i < 4; i++)
#pragma unroll
        for (int j = 0; j < 4; j++) acc[i][j] = (f32x4){0.f, 0.f, 0.f, 0.f};

    const int ar = tid >> 2;
    const int ac = (((tid & 3) ^ ((ar >> 1) & 3)) * 8);
    const int rsw = ((l16 >> 1) & 3);

    const ushort_t* aptr = A + (size_t)(mBase + ar) * K + ac;
    const ushort_t* bptr = B + (size_t)(nBase + ar) * K + ac;

#define G1_STAGE(buf, k0)                                                            \
    {                                                                                \
        _Pragma("unroll") for (int c = 0; c < 2; c++) {                              \
            gload_lds16(aptr + (size_t)(c * 64) * K + (k0), lA[buf] + c * 2048 + wave * 512); \
            gload_lds16(bptr + (size_t)(c * 64) * K + (k0), lB[buf] + c * 2048 + wave * 512); \
        }                                                                            \
    }

    G1_STAGE(0, 0);
    for (int k0 = 0; k0 < K; k0 += 32) {
        const int cur = (k0 >> 5) & 1;
        __syncthreads();
        if (k0 + 32 < K) G1_STAGE(cur ^ 1, k0 + 32);

        short8 af[4], bf[4];
#pragma unroll
        for (int i = 0; i < 4; i++)
            af[i] = *(const short8*)(lA[cur] + (wr * 64 + i * 16 + l16) * 32 + ((quad ^ rsw) * 8));
#pragma unroll
        for (int j = 0; j < 4; j++)
            bf[j] = *(const short8*)(lB[cur] + (wc * 64 + j * 16 + l16) * 32 + ((quad ^ rsw) * 8));
#pragma unroll
        for (int i = 0; i < 4; i++)
#pragma unroll
            for (int j = 0; j < 4; j++)
                acc[i][j] = __builtin_amdgcn_mfma_f32_16x16x32_bf16(af[i], bf[j], acc[i][j], 0, 0, 0);
    }

    if (nBase >= 2048) {
#pragma unroll
        for (int i = 0; i < 4; i++)
#pragma unroll
            for (int j = 0; j < 4; j++) {
                const int row0 = mBase + wr * 64 + i * 16 + quad * 4;
                const int col = nBase + wc * 64 + j * 16 + l16 - 2048;
                const int b = row0 >> 11, s0 = row0 & 2047;
                uint2 pk;
                pk.x = pk2bf(acc[i][j][0], acc[i][j][1]);
                pk.y = pk2bf(acc[i][j][2], acc[i][j][3]);
                *(uint2*)(vT + ((size_t)(b * 16) * 64 + col) * 2048 + s0) = pk;
            }
        return;
    }
    const float cs = (nBase < 1024) ? qScale : 1.0f;
#pragma unroll
    for (int i = 0; i < 4; i++)
#pragma unroll
        for (int j = 0; j < 4; j++)
#pragma unroll
            for (int r = 0; r < 4; r++) {
                const int row = mBase + wr * 64 + i * 16 + quad * 4 + r;
                const int col = nBase + wc * 64 + j * 16 + l16;
                Cb[(size_t)row * ldc + col] = f2bf(acc[i][j][r] * cs);
            }
}

// ---------------- GEMM2: out = o·Wout^T + bias, 64x128 tile, BK=64, dbuf (round-5) ----------------
__global__ __launch_bounds__(256, 2)
void gemm_out(const ushort_t* __restrict__ A, const ushort_t* __restrict__ B,
              float* __restrict__ Cf, const float* __restrict__ bias,
              int M, int N, int K) {
    __shared__ ushort_t lA[2][64 * 64];
    __shared__ ushort_t lB[2][128 * 64];
    const int tid = threadIdx.x;
    const int wave = tid >> 6, lane = tid & 63;
    const int quad = lane >> 4, l16 = lane & 15;
    const int mBase = blockIdx.y * 64, nBase = blockIdx.x * 128;

    f32x4 acc[4][2];
#pragma unroll
    for (int i = 0; i < 4; i++)
#pragma unroll
        for (int j = 0; j < 2; j++) acc[i][j] = (f32x4){0.f, 0.f, 0.f, 0.f};

    const int sr = tid >> 3;
    const int sc = ((tid & 7) ^ (sr & 7)) * 8;
    const int swz = l16 & 7;

    const ushort_t* aptr = A + (size_t)(mBase + sr) * K + sc;
    const ushort_t* bptr = B + (size_t)(nBase + sr) * K + sc;

#define G2_STAGE(buf, k0)                                                              \
    {                                                                                  \
        _Pragma("unroll") for (int c = 0; c < 2; c++)                                  \
            gload_lds16(aptr + (size_t)(c * 32) * K + (k0), lA[buf] + c * 2048 + wave * 512); \
        _Pragma("unroll") for (int c = 0; c < 4; c++)                                  \
            gload_lds16(bptr + (size_t)(c * 32) * K + (k0), lB[buf] + c * 2048 + wave * 512); \
    }

    G2_STAGE(0, 0);
    for (int k0 = 0; k0 < K; k0 += 64) {
        const int cur = (k0 >> 6) & 1;
        __syncthreads();
        if (k0 + 64 < K) G2_STAGE(cur ^ 1, k0 + 64);

#pragma unroll
        for (int ks = 0; ks < 2; ks++) {
            short8 af[4], bf[2];
#pragma unroll
            for (int i = 0; i < 4; i++)
                af[i] = *(const short8*)(lA[cur] + (i * 16 + l16) * 64 + (((ks * 4 + quad) ^ swz) * 8));
#pragma unroll
            for (int j = 0; j < 2; j++)
                bf[j] = *(const short8*)(lB[cur] + (wave * 32 + j * 16 + l16) * 64 + (((ks * 4 + quad) ^ swz) * 8));
#pragma unroll
            for (int i = 0; i < 4; i++)
#pragma unroll
                for (int j = 0; j < 2; j++)
                    acc[i][j] = __builtin_amdgcn_mfma_f32_16x16x32_bf16(af[i], bf[j], acc[i][j], 0, 0, 0);
        }
    }

#pragma unroll
    for (int i = 0; i < 4; i++)
#pragma unroll
        for (int j = 0; j < 2; j++)
#pragma unroll
            for (int r = 0; r < 4; r++) {
                const int row = mBase + i * 16 + quad * 4 + r;
                const int col = nBase + wave * 32 + j * 16 + l16;
                Cf[(size_t)row * N + col] = acc[i][j][r] + bias[col];
            }
}

// ---------------- fused flash attention: qt=2, key-split waves ----------------
// 512 thr = 8 waves = 4 q-groups (32 q each) x 2 key-halves. Bq=128, key-tile 64 dbuf.
// grid (16,32) = 512 blocks = 2/CU -> 16 waves/CU; VGPR ~110 keeps 4 waves/SIMD.
// Per wave-iter: 10 b128 reads feed 18 MFMA (round-5 was 18/18 — LDS-bound).
// smem ushort: [0,8192) K dbuf | [8192,16384) V^T dbuf | [16384,26624) lP 8x(32x40)
// (lP region doubles as Q staging pre-loop; whole smem as f32 scratch post-loop).
__global__ __launch_bounds__(512, 4)
void attn_flash(const ushort_t* __restrict__ qk, const ushort_t* __restrict__ vT,
                ushort_t* __restrict__ o) {
    __shared__ ushort_t smem[26624];

    const int tid = threadIdx.x;
    const int wave = tid >> 6, lane = tid & 63;
    const int quad = lane >> 4, l16 = lane & 15;
    const int qg = wave & 3, kg = wave >> 2;
    const int bh = blockIdx.y, b = bh >> 4, h = bh & 15;
    const size_t rowBase = (size_t)b * 2048;
    const int qCol = h * 64, kCol = 1024 + h * 64;
    const int qRow0 = blockIdx.x * 128;
    const int swz = l16 & 7;

    ushort_t* lP = smem + 16384 + wave * 1280;  // [32 q][32 k] stride 40 (conflict-free)

    // ---- stage Q 128x64 (pre-scaled by SC) into lP region, pull B-frags ----
    {
        const int sr_ = tid >> 3;
        const int sc_ = ((tid & 7) ^ (sr_ & 7)) * 8;
#pragma unroll
        for (int cc = 0; cc < 2; cc++)
            gload_lds16(qk + (rowBase + qRow0 + cc * 64 + sr_) * 2048 + qCol + sc_,
                        smem + 16384 + cc * 4096 + wave * 512);
    }
    __syncthreads();
    short8 qf[2][2];  // [qt][ks]
#pragma unroll
    for (int qt = 0; qt < 2; qt++)
#pragma unroll
        for (int ks = 0; ks < 2; ks++)
            qf[qt][ks] = *(const short8*)(smem + 16384 + (qg * 32 + qt * 16 + l16) * 64 +
                                          (((ks * 4 + quad) ^ swz) * 8));
    __syncthreads();  // Q reads done; lP region free

    short8 onesA;
#pragma unroll
    for (int i = 0; i < 8; i++) onesA[i] = (short)0x3F80;

    f32x4 oacc[4][2];  // [dt][qt]
    f32x4 lacc[2];     // [qt], entries replicate l
#pragma unroll
    for (int qt = 0; qt < 2; qt++) {
        lacc[qt] = (f32x4){0.f, 0.f, 0.f, 0.f};
#pragma unroll
        for (int dt = 0; dt < 4; dt++) oacc[dt][qt] = (f32x4){0.f, 0.f, 0.f, 0.f};
    }

    // staging: 64 rows x 8 chunks = 512 loads = 1 per thread per buffer
    const int sr = tid >> 3;
    const int sch = ((tid & 7) ^ (sr & 7)) * 8;
    const ushort_t* kptr = qk + (rowBase + sr) * 2048 + kCol + sch;
    const ushort_t* vptr = vT + ((size_t)bh * 64 + sr) * 2048 + sch;

#define AT_STAGE(buf, kt)                                                            \
    {                                                                                \
        gload_lds16(kptr + (size_t)(kt) * 64 * 2048, smem + (buf) * 4096 + wave * 512); \
        gload_lds16(vptr + (kt) * 64, smem + 8192 + (buf) * 4096 + wave * 512);      \
    }

    AT_STAGE(0, 0);
    for (int kt = 0; kt < 32; kt++) {
        const int cur = kt & 1;
        __syncthreads();  // drains tile kt (issued one iteration ago)
        if (kt < 31) AT_STAGE(cur ^ 1, kt + 1);
        const ushort_t* lK = smem + cur * 4096;
        const ushort_t* lV = smem + 8192 + cur * 4096;

        // ---- S^T = K·Q^T on this wave's 32 keys x 32 q: 4 reads, 8 MFMA ----
        f32x4 sacc[2][2];  // [mh][qt]
#pragma unroll
        for (int mh = 0; mh < 2; mh++) {
            const int krow = kg * 32 + mh * 16 + l16;
            const short8 k0 = *(const short8*)(lK + krow * 64 + ((quad ^ swz) * 8));
            const short8 k1 = *(const short8*)(lK + krow * 64 + (((4 + quad) ^ swz) * 8));
#pragma unroll
            for (int qt = 0; qt < 2; qt++) {
                f32x4 t = (f32x4){0.f, 0.f, 0.f, 0.f};
                t = __builtin_amdgcn_mfma_f32_16x16x32_bf16(k0, qf[qt][0], t, 0, 0, 0);
                t = __builtin_amdgcn_mfma_f32_16x16x32_bf16(k1, qf[qt][1], t, 0, 0, 0);
                sacc[mh][qt] = t;
            }
        }

        // ---- P = exp2(S^T) -> per-wave lP (stride 40, conflict-free) ----
#pragma unroll
        for (int qt = 0; qt < 2; qt++)
#pragma unroll
            for (int mh = 0; mh < 2; mh++) {
                const f32x4 s = sacc[mh][qt];
                uint2 pk;
                pk.x = pk2bf(EXP2F(s[0]), EXP2F(s[1]));
                pk.y = pk2bf(EXP2F(s[2]), EXP2F(s[3]));
                *(uint2*)(&lP[(qt * 16 + l16) * 40 + mh * 16 + quad * 4]) = pk;
            }

        // ---- P·V (+ones·P for l): 6 reads feed 10 MFMA ----
        short8 pf[2];
#pragma unroll
        for (int qt = 0; qt < 2; qt++) {
            pf[qt] = *(const short8*)(&lP[(qt * 16 + l16) * 40 + quad * 8]);
            lacc[qt] = __builtin_amdgcn_mfma_f32_16x16x32_bf16(onesA, pf[qt], lacc[qt], 0, 0, 0);
        }
#pragma unroll
        for (int dt = 0; dt < 4; dt++) {
            const short8 vf = *(const short8*)(lV + (dt * 16 + l16) * 64 +
                                               (((kg * 4 + quad) ^ swz) * 8));
#pragma unroll
            for (int qt = 0; qt < 2; qt++)
                oacc[dt][qt] = __builtin_amdgcn_mfma_f32_16x16x32_bf16(vf, pf[qt], oacc[dt][qt], 0, 0, 0);
        }
    }

    // ---- epilogue: combine the two key-halves through LDS, write O ----
    __syncthreads();  // all waves done with smem tiles
    float* red = (float*)smem;  // 13312 floats; [0,8192) oacc, [8192,8320) l
    if (kg == 1) {
#pragma unroll
        for (int qt = 0; qt < 2; qt++) {
            if (quad == 0) red[8192 + qg * 32 + qt * 16 + l16] = lacc[qt][0];
#pragma unroll
            for (int dt = 0; dt < 4; dt++)
                *(f32x4*)(red + (((qg * 4 + dt) * 2 + qt) * 64 + lane) * 4) = oacc[dt][qt];
        }
    }
    __syncthreads();
    if (kg == 0) {
        float linv[2];
#pragma unroll
        for (int qt = 0; qt < 2; qt++)
            linv[qt] = 1.0f / (lacc[qt][0] + red[8192 + qg * 32 + qt * 16 + l16]);
#pragma unroll
        for (int qt = 0; qt < 2; qt++) {
            const size_t row = rowBase + qRow0 + qg * 32 + qt * 16 + l16;
#pragma unroll
            for (int dt = 0; dt < 4; dt++) {
                const f32x4 r = *(const f32x4*)(red + (((qg * 4 + dt) * 2 + qt) * 64 + lane) * 4);
                uint2 pk;
                pk.x = pk2bf((oacc[dt][qt][0] + r[0]) * linv[qt],
                             (oacc[dt][qt][1] + r[1]) * linv[qt]);
                pk.y = pk2bf((oacc[dt][qt][2] + r[2]) * linv[qt],
                             (oacc[dt][qt][3] + r[3]) * linv[qt]);
                *(uint2*)(o + row * 1024 + h * 64 + dt * 16 + quad * 4) = pk;
            }
        }
    }
}

extern "C" void kernel_launch(void* const* d_in, const int* in_sizes, int n_in,
                              void* d_out, int out_size, void* d_ws, size_t ws_size,
                              hipStream_t stream) {
    const float* x    = (const float*)d_in[0];
    const float* Wqkv = (const float*)d_in[1];
    const float* Wout = (const float*)d_in[2];
    const float* bout = (const float*)d_in[3];
    float* out = (float*)d_out;

    ushort_t* xb    = (ushort_t*)d_ws;                    // 4096*1024
    ushort_t* wqkvb = xb + (size_t)4096 * 1024;           // 3072*1024
    ushort_t* woutb = wqkvb + (size_t)3072 * 1024;        // 1024*1024
    ushort_t* qkb   = woutb + (size_t)1024 * 1024;        // 4096*2048 (Q*SC, K)
    ushort_t* vTb   = qkb + (size_t)4096 * 2048;          // 32*64*2048 (V^T)
    ushort_t* ob    = xb;                                 // alias: x dead after GEMM1

    const float SC = 0.125f * 1.44269504089f;  // SCALE * log2(e)

    cvt_all<<<8192, 256, 0, stream>>>(x, xb, Wqkv, wqkvb, Wout, woutb);
    gemm_qkv<<<dim3(24, 32), 256, 0, stream>>>(xb, wqkvb, qkb, vTb, 4096, 3072, 1024, 2048, SC);
    attn_flash<<<dim3(16, 32), 512, 0, stream>>>(qkb, vTb, ob);
    gemm_out<<<dim3(8, 64), 256, 0, stream>>>(ob, woutb, out, bout, 4096, 1024, 1024);
}

// Round 8
// 177.482 us; speedup vs baseline: 1.5255x; 1.0221x over previous
//
#include <hip/hip_runtime.h>

// MHSA: B=2, S=2048, D=1024, H=16, hd=64. fp32 in/out, bf16 MFMA internally.
// cvt(all) -> gemm_qkv(Q*SC,K + V^T split, LDS dbuf) -> flash attn (S^T, qt=4, 2qg x 2kg)
//          -> gemm_out(+bias, LDS dbuf)

typedef __attribute__((ext_vector_type(8))) short short8;
typedef __attribute__((ext_vector_type(4))) float f32x4;
typedef unsigned short ushort_t;
typedef unsigned int uint32;

#define AS1 __attribute__((address_space(1)))
#define AS3 __attribute__((address_space(3)))

__device__ __forceinline__ void gload_lds16(const void* gp, void* lp) {
    __builtin_amdgcn_global_load_lds((const AS1 void*)gp, (AS3 void*)lp, 16, 0, 0);
}

#if __has_builtin(__builtin_amdgcn_exp2f)
#define EXP2F(x) __builtin_amdgcn_exp2f(x)
#else
#define EXP2F(x) exp2f(x)
#endif

__device__ __forceinline__ uint32 rhu(float f) { return __float_as_uint(f) + 0x8000u; }
#if __has_builtin(__builtin_amdgcn_perm)
__device__ __forceinline__ uint32 pk2bf(float a, float b) {
    return __builtin_amdgcn_perm(rhu(b), rhu(a), 0x07060302u);
}
#else
__device__ __forceinline__ uint32 pk2bf(float a, float b) {
    return (rhu(a) >> 16) | (rhu(b) & 0xffff0000u);
}
#endif
__device__ __forceinline__ ushort_t f2bf(float f) { return (ushort_t)(rhu(f) >> 16); }

// ---------------- fused fp32 -> bf16 convert ----------------
__global__ void cvt_all(const float* __restrict__ x, ushort_t* __restrict__ xb,
                        const float* __restrict__ wq, ushort_t* __restrict__ wqb,
                        const float* __restrict__ wo, ushort_t* __restrict__ wob) {
    int blk = blockIdx.x;
    const float* in; ushort_t* out;
    if (blk < 4096)      { in = x;  out = xb;  }
    else if (blk < 7168) { in = wq; out = wqb; blk -= 4096; }
    else                 { in = wo; out = wob; blk -= 7168; }
    const int i = (blk * 256 + threadIdx.x) * 4;
    const float4 v = *(const float4*)(in + i);
    uint2 pk;
    pk.x = pk2bf(v.x, v.y);
    pk.y = pk2bf(v.z, v.w);
    *(uint2*)(out + i) = pk;
}

// ---------------- GEMM1: qkv = x·Wqkv^T, 128x128 tile, BK=32, dbuf ----------------
__global__ __launch_bounds__(256, 2)
void gemm_qkv(const ushort_t* __restrict__ A, const ushort_t* __restrict__ B,
              ushort_t* __restrict__ Cb, ushort_t* __restrict__ vT,
              int M, int N, int K, int ldc, float qScale) {
    __shared__ ushort_t lA[2][128 * 32];
    __shared__ ushort_t lB[2][128 * 32];
    const int tid = threadIdx.x;
    const int wave = tid >> 6, lane = tid & 63;
    const int quad = lane >> 4, l16 = lane & 15;
    const int wr = wave >> 1, wc = wave & 1;
    const int mBase = blockIdx.y * 128, nBase = blockIdx.x * 128;

    f32x4 acc[4][4];
#pragma unroll
    for (int i = 0; i < 4; i++)
#pragma unroll
        for (int j = 0; j < 4; j++) acc[i][j] = (f32x4){0.f, 0.f, 0.f, 0.f};

    const int ar = tid >> 2;
    const int ac = (((tid & 3) ^ ((ar >> 1) & 3)) * 8);
    const int rsw = ((l16 >> 1) & 3);

    const ushort_t* aptr = A + (size_t)(mBase + ar) * K + ac;
    const ushort_t* bptr = B + (size_t)(nBase + ar) * K + ac;

#define G1_STAGE(buf, k0)                                                            \
    {                                                                                \
        _Pragma("unroll") for (int c = 0; c < 2; c++) {                              \
            gload_lds16(aptr + (size_t)(c * 64) * K + (k0), lA[buf] + c * 2048 + wave * 512); \
            gload_lds16(bptr + (size_t)(c * 64) * K + (k0), lB[buf] + c * 2048 + wave * 512); \
        }                                                                            \
    }

    G1_STAGE(0, 0);
    for (int k0 = 0; k0 < K; k0 += 32) {
        const int cur = (k0 >> 5) & 1;
        __syncthreads();
        if (k0 + 32 < K) G1_STAGE(cur ^ 1, k0 + 32);

        short8 af[4], bf[4];
#pragma unroll
        for (int i = 0; i < 4; i++)
            af[i] = *(const short8*)(lA[cur] + (wr * 64 + i * 16 + l16) * 32 + ((quad ^ rsw) * 8));
#pragma unroll
        for (int j = 0; j < 4; j++)
            bf[j] = *(const short8*)(lB[cur] + (wc * 64 + j * 16 + l16) * 32 + ((quad ^ rsw) * 8));
#pragma unroll
        for (int i = 0; i < 4; i++)
#pragma unroll
            for (int j = 0; j < 4; j++)
                acc[i][j] = __builtin_amdgcn_mfma_f32_16x16x32_bf16(af[i], bf[j], acc[i][j], 0, 0, 0);
    }

    if (nBase >= 2048) {
#pragma unroll
        for (int i = 0; i < 4; i++)
#pragma unroll
            for (int j = 0; j < 4; j++) {
                const int row0 = mBase + wr * 64 + i * 16 + quad * 4;
                const int col = nBase + wc * 64 + j * 16 + l16 - 2048;
                const int b = row0 >> 11, s0 = row0 & 2047;
                uint2 pk;
                pk.x = pk2bf(acc[i][j][0], acc[i][j][1]);
                pk.y = pk2bf(acc[i][j][2], acc[i][j][3]);
                *(uint2*)(vT + ((size_t)(b * 16) * 64 + col) * 2048 + s0) = pk;
            }
        return;
    }
    const float cs = (nBase < 1024) ? qScale : 1.0f;
#pragma unroll
    for (int i = 0; i < 4; i++)
#pragma unroll
        for (int j = 0; j < 4; j++)
#pragma unroll
            for (int r = 0; r < 4; r++) {
                const int row = mBase + wr * 64 + i * 16 + quad * 4 + r;
                const int col = nBase + wc * 64 + j * 16 + l16;
                Cb[(size_t)row * ldc + col] = f2bf(acc[i][j][r] * cs);
            }
}

// ---------------- GEMM2: out = o·Wout^T + bias, 64x128 tile, BK=64, dbuf ----------------
__global__ __launch_bounds__(256, 2)
void gemm_out(const ushort_t* __restrict__ A, const ushort_t* __restrict__ B,
              float* __restrict__ Cf, const float* __restrict__ bias,
              int M, int N, int K) {
    __shared__ ushort_t lA[2][64 * 64];
    __shared__ ushort_t lB[2][128 * 64];
    const int tid = threadIdx.x;
    const int wave = tid >> 6, lane = tid & 63;
    const int quad = lane >> 4, l16 = lane & 15;
    const int mBase = blockIdx.y * 64, nBase = blockIdx.x * 128;

    f32x4 acc[4][2];
#pragma unroll
    for (int i = 0; i < 4; i++)
#pragma unroll
        for (int j = 0; j < 2; j++) acc[i][j] = (f32x4){0.f, 0.f, 0.f, 0.f};

    const int sr = tid >> 3;
    const int sc = ((tid & 7) ^ (sr & 7)) * 8;
    const int swz = l16 & 7;

    const ushort_t* aptr = A + (size_t)(mBase + sr) * K + sc;
    const ushort_t* bptr = B + (size_t)(nBase + sr) * K + sc;

#define G2_STAGE(buf, k0)                                                              \
    {                                                                                  \
        _Pragma("unroll") for (int c = 0; c < 2; c++)                                  \
            gload_lds16(aptr + (size_t)(c * 32) * K + (k0), lA[buf] + c * 2048 + wave * 512); \
        _Pragma("unroll") for (int c = 0; c < 4; c++)                                  \
            gload_lds16(bptr + (size_t)(c * 32) * K + (k0), lB[buf] + c * 2048 + wave * 512); \
    }

    G2_STAGE(0, 0);
    for (int k0 = 0; k0 < K; k0 += 64) {
        const int cur = (k0 >> 6) & 1;
        __syncthreads();
        if (k0 + 64 < K) G2_STAGE(cur ^ 1, k0 + 64);

#pragma unroll
        for (int ks = 0; ks < 2; ks++) {
            short8 af[4], bf[2];
#pragma unroll
            for (int i = 0; i < 4; i++)
                af[i] = *(const short8*)(lA[cur] + (i * 16 + l16) * 64 + (((ks * 4 + quad) ^ swz) * 8));
#pragma unroll
            for (int j = 0; j < 2; j++)
                bf[j] = *(const short8*)(lB[cur] + (wave * 32 + j * 16 + l16) * 64 + (((ks * 4 + quad) ^ swz) * 8));
#pragma unroll
            for (int i = 0; i < 4; i++)
#pragma unroll
                for (int j = 0; j < 2; j++)
                    acc[i][j] = __builtin_amdgcn_mfma_f32_16x16x32_bf16(af[i], bf[j], acc[i][j], 0, 0, 0);
        }
    }

#pragma unroll
    for (int i = 0; i < 4; i++)
#pragma unroll
        for (int j = 0; j < 2; j++)
#pragma unroll
            for (int r = 0; r < 4; r++) {
                const int row = mBase + i * 16 + quad * 4 + r;
                const int col = nBase + wave * 32 + j * 16 + l16;
                Cf[(size_t)row * N + col] = acc[i][j][r] + bias[col];
            }
}

// ---------------- fused flash attention: qt=4, 2 q-groups x 2 key-halves ----------------
// 256 thr = 4 waves. Bq=128: wave owns 64 q (qg) x 32 keys (kg) of each 64-key dbuf tile.
// grid (16,32) = 512 blocks = 2/CU (two independent barrier domains per CU).
// Per wave-iter: 12 b128 reads + 8 b64 writes feed 36 MFMA (round-7: 10r+4w per 18).
// smem ushort: [0,8192) K dbuf | [8192,16384) V^T dbuf | [16384,26624) lP 4x(64x40)
// (lP region doubles as Q staging pre-loop; smem as f32 scratch post-loop).
__global__ __launch_bounds__(256, 2)
void attn_flash(const ushort_t* __restrict__ qk, const ushort_t* __restrict__ vT,
                ushort_t* __restrict__ o) {
    __shared__ ushort_t smem[26624];

    const int tid = threadIdx.x;
    const int wave = tid >> 6, lane = tid & 63;
    const int quad = lane >> 4, l16 = lane & 15;
    const int qg = wave & 1, kg = wave >> 1;
    const int bh = blockIdx.y, b = bh >> 4, h = bh & 15;
    const size_t rowBase = (size_t)b * 2048;
    const int qCol = h * 64, kCol = 1024 + h * 64;
    const int qRow0 = blockIdx.x * 128;
    const int swz = l16 & 7;

    ushort_t* lP = smem + 16384 + wave * 2560;  // [64 q][32 k] stride 40 (conflict-free)

    // staging geometry: 32 rows x 8 chunks per pass, XOR chunk swizzle
    const int sr = tid >> 3;                       // 0..31
    const int sc = ((tid & 7) ^ (sr & 7)) * 8;

    // ---- stage Q 128x64 (pre-scaled by SC) into lP region, pull B-frags ----
#pragma unroll
    for (int cc = 0; cc < 4; cc++)
        gload_lds16(qk + (rowBase + qRow0 + cc * 32 + sr) * 2048 + qCol + sc,
                    smem + 16384 + cc * 2048 + wave * 512);
    __syncthreads();
    short8 qf[4][2];  // [qt][ks]: q = qg*64 + qt*16 + l16
#pragma unroll
    for (int qt = 0; qt < 4; qt++)
#pragma unroll
        for (int ks = 0; ks < 2; ks++)
            qf[qt][ks] = *(const short8*)(smem + 16384 + (qg * 64 + qt * 16 + l16) * 64 +
                                          (((ks * 4 + quad) ^ swz) * 8));
    // NOTE: Q reads are ordered before iter-0's lP writes by the loop's first barrier.

    short8 onesA;
#pragma unroll
    for (int i = 0; i < 8; i++) onesA[i] = (short)0x3F80;

    f32x4 oacc[4][4];  // [dt][qt]
    f32x4 lacc[4];     // [qt], entries replicate l
#pragma unroll
    for (int qt = 0; qt < 4; qt++) {
        lacc[qt] = (f32x4){0.f, 0.f, 0.f, 0.f};
#pragma unroll
        for (int dt = 0; dt < 4; dt++) oacc[dt][qt] = (f32x4){0.f, 0.f, 0.f, 0.f};
    }

    const ushort_t* kptr = qk + (rowBase + sr) * 2048 + kCol + sc;
    const ushort_t* vptr = vT + ((size_t)bh * 64 + sr) * 2048 + sc;

#define AT_STAGE(buf, kt)                                                              \
    {                                                                                  \
        _Pragma("unroll") for (int cc = 0; cc < 2; cc++)                               \
            gload_lds16(kptr + (size_t)((kt) * 64 + cc * 32) * 2048,                   \
                        smem + (buf) * 4096 + cc * 2048 + wave * 512);                 \
        _Pragma("unroll") for (int cc = 0; cc < 2; cc++)                               \
            gload_lds16(vptr + (size_t)(cc * 32) * 2048 + (kt) * 64,                   \
                        smem + 8192 + (buf) * 4096 + cc * 2048 + wave * 512);          \
    }

    AT_STAGE(0, 0);
    for (int kt = 0; kt < 32; kt++) {
        const int cur = kt & 1;
        __syncthreads();  // drains tile kt (issued one iteration ago)
        if (kt < 31) AT_STAGE(cur ^ 1, kt + 1);
        const ushort_t* lK = smem + cur * 4096;
        const ushort_t* lV = smem + 8192 + cur * 4096;

        // ---- S^T = K·Q^T on 32 keys x 64 q: 4 reads feed 16 MFMA ----
        f32x4 sacc[2][4];  // [mh][qt]
#pragma unroll
        for (int mh = 0; mh < 2; mh++) {
            const int krow = kg * 32 + mh * 16 + l16;
            const short8 k0 = *(const short8*)(lK + krow * 64 + ((quad ^ swz) * 8));
            const short8 k1 = *(const short8*)(lK + krow * 64 + (((4 + quad) ^ swz) * 8));
#pragma unroll
            for (int qt = 0; qt < 4; qt++) {
                f32x4 t = (f32x4){0.f, 0.f, 0.f, 0.f};
                t = __builtin_amdgcn_mfma_f32_16x16x32_bf16(k0, qf[qt][0], t, 0, 0, 0);
                t = __builtin_amdgcn_mfma_f32_16x16x32_bf16(k1, qf[qt][1], t, 0, 0, 0);
                sacc[mh][qt] = t;
            }
        }

        // ---- P = exp2(S^T) -> per-wave lP (stride 40) ----
#pragma unroll
        for (int qt = 0; qt < 4; qt++)
#pragma unroll
            for (int mh = 0; mh < 2; mh++) {
                const f32x4 s = sacc[mh][qt];
                uint2 pk;
                pk.x = pk2bf(EXP2F(s[0]), EXP2F(s[1]));
                pk.y = pk2bf(EXP2F(s[2]), EXP2F(s[3]));
                *(uint2*)(&lP[(qt * 16 + l16) * 40 + mh * 16 + quad * 4]) = pk;
            }

        // ---- P·V (+ones·P for l): 8 reads feed 20 MFMA ----
        short8 pf[4];
#pragma unroll
        for (int qt = 0; qt < 4; qt++) {
            pf[qt] = *(const short8*)(&lP[(qt * 16 + l16) * 40 + quad * 8]);
            lacc[qt] = __builtin_amdgcn_mfma_f32_16x16x32_bf16(onesA, pf[qt], lacc[qt], 0, 0, 0);
        }
#pragma unroll
        for (int dt = 0; dt < 4; dt++) {
            const short8 vf = *(const short8*)(lV + (dt * 16 + l16) * 64 +
                                               (((kg * 4 + quad) ^ swz) * 8));
#pragma unroll
            for (int qt = 0; qt < 4; qt++)
                oacc[dt][qt] = __builtin_amdgcn_mfma_f32_16x16x32_bf16(vf, pf[qt], oacc[dt][qt], 0, 0, 0);
        }
    }

    // ---- epilogue: combine the two key-halves through LDS, write O ----
    __syncthreads();  // all waves done with smem tiles
    float* red = (float*)smem;  // [0,8192) oacc f32, [8192,8448) l
    if (kg == 1) {
#pragma unroll
        for (int qt = 0; qt < 4; qt++) {
            if (quad == 0) red[8192 + qg * 64 + qt * 16 + l16] = lacc[qt][0];
#pragma unroll
            for (int dt = 0; dt < 4; dt++)
                *(f32x4*)(red + (((qg * 4 + dt) * 4 + qt) * 64 + lane) * 4) = oacc[dt][qt];
        }
    }
    __syncthreads();
    if (kg == 0) {
        float linv[4];
#pragma unroll
        for (int qt = 0; qt < 4; qt++)
            linv[qt] = 1.0f / (lacc[qt][0] + red[8192 + qg * 64 + qt * 16 + l16]);
#pragma unroll
        for (int qt = 0; qt < 4; qt++) {
            const size_t row = rowBase + qRow0 + qg * 64 + qt * 16 + l16;
#pragma unroll
            for (int dt = 0; dt < 4; dt++) {
                const f32x4 r = *(const f32x4*)(red + (((qg * 4 + dt) * 4 + qt) * 64 + lane) * 4);
                uint2 pk;
                pk.x = pk2bf((oacc[dt][qt][0] + r[0]) * linv[qt],
                             (oacc[dt][qt][1] + r[1]) * linv[qt]);
                pk.y = pk2bf((oacc[dt][qt][2] + r[2]) * linv[qt],
                             (oacc[dt][qt][3] + r[3]) * linv[qt]);
                *(uint2*)(o + row * 1024 + h * 64 + dt * 16 + quad * 4) = pk;
            }
        }
    }
}

extern "C" void kernel_launch(void* const* d_in, const int* in_sizes, int n_in,
                              void* d_out, int out_size, void* d_ws, size_t ws_size,
                              hipStream_t stream) {
    const float* x    = (const float*)d_in[0];
    const float* Wqkv = (const float*)d_in[1];
    const float* Wout = (const float*)d_in[2];
    const float* bout = (const float*)d_in[3];
    float* out = (float*)d_out;

    ushort_t* xb    = (ushort_t*)d_ws;                    // 4096*1024
    ushort_t* wqkvb = xb + (size_t)4096 * 1024;           // 3072*1024
    ushort_t* woutb = wqkvb + (size_t)3072 * 1024;        // 1024*1024
    ushort_t* qkb   = woutb + (size_t)1024 * 1024;        // 4096*2048 (Q*SC, K)
    ushort_t* vTb   = qkb + (size_t)4096 * 2048;          // 32*64*2048 (V^T)
    ushort_t* ob    = xb;                                 // alias: x dead after GEMM1

    const float SC = 0.125f * 1.44269504089f;  // SCALE * log2(e)

    cvt_all<<<8192, 256, 0, stream>>>(x, xb, Wqkv, wqkvb, Wout, woutb);
    gemm_qkv<<<dim3(24, 32), 256, 0, stream>>>(xb, wqkvb, qkb, vTb, 4096, 3072, 1024, 2048, SC);
    attn_flash<<<dim3(16, 32), 256, 0, stream>>>(qkb, vTb, ob);
    gemm_out<<<dim3(8, 64), 256, 0, stream>>>(ob, woutb, out, bout, 4096, 1024, 1024);
}